// Round 1
// baseline (660.008 us; speedup 1.0000x reference)
//
#include <hip/hip_runtime.h>
#include <math.h>

#define NB 4
#define L 4096
#define D 64
#define TQ 8          // queries per wave
#define CB 2          // columns per lane per tile
#define TCOLS 128     // K-tile columns (CB * 64)
#define NTILES (L / TCOLS)

// Zero-fill the dense attn region (poisoned 0xAA before every launch).
__global__ void zero_kernel(float4* __restrict__ p, unsigned int n4) {
    unsigned int i = blockIdx.x * blockDim.x + threadIdx.x;
    unsigned int stride = gridDim.x * blockDim.x;
    float4 z = make_float4(0.f, 0.f, 0.f, 0.f);
    for (; i < n4; i += stride) p[i] = z;
}

__global__ __launch_bounds__(256, 2)
void sparse_attn_kernel(const float* __restrict__ qg,
                        const float* __restrict__ kg,
                        const float* __restrict__ vg,
                        float* __restrict__ outg) {
    // K tile: [col][dh] as float2, dh = d/2. Stride 33 float2 (66 floats):
    // lane address delta 66*4B -> bank stride 2 -> only 2-way aliasing (free).
    __shared__ float2 skt[TCOLS][D / 2 + 1];
    __shared__ float  sq[32][D];   // 32 queries per block

    const int tid  = threadIdx.x;
    const int lane = tid & 63;
    const int wid  = tid >> 6;
    const int qblock = blockIdx.x * 32;          // 32 queries / block
    const int b = qblock >> 12;                  // qblock / L  (uniform per block)
    const float* kb = kg + (size_t)b * L * D;
    const float* vb = vg + (size_t)b * L * D;
    float* attng = outg + (size_t)NB * L * D;    // attn region follows out region

    // Stage Q (32 rows x 64) -- coalesced
    for (int i = tid; i < 32 * D; i += 256)
        sq[i >> 6][i & 63] = qg[(size_t)qblock * D + i];

    float Z[TQ];
    float tv[TQ][5];
    int   tc[TQ][5];
#pragma unroll
    for (int t = 0; t < TQ; ++t) {
        Z[t] = 0.f;
#pragma unroll
        for (int i = 0; i < 5; ++i) { tv[t][i] = -INFINITY; tc[t][i] = -1; }
    }

    for (int g = 0; g < NTILES; ++g) {
        __syncthreads();
        // Stage K tile: cols [g*TCOLS, g*TCOLS+TCOLS). Coalesced float2 loads.
        for (int i = tid; i < TCOLS * (D / 2); i += 256) {
            int col = i >> 5;          // 32 float2 per column
            int dh  = i & 31;
            skt[col][dh] = *(const float2*)(kb + (size_t)(g * TCOLS + col) * D + dh * 2);
        }
        __syncthreads();

        float acc[TQ][CB];
#pragma unroll
        for (int t = 0; t < TQ; ++t)
#pragma unroll
            for (int c = 0; c < CB; ++c) acc[t][c] = 0.f;

#pragma unroll 4
        for (int dh = 0; dh < D / 2; ++dh) {
            float2 qq[TQ];
#pragma unroll
            for (int t = 0; t < TQ; ++t)
                qq[t] = *(const float2*)&sq[wid * TQ + t][dh * 2];  // LDS broadcast
#pragma unroll
            for (int c = 0; c < CB; ++c) {
                float2 kk = skt[c * 64 + lane][dh];
#pragma unroll
                for (int t = 0; t < TQ; ++t) {
                    acc[t][c] = fmaf(qq[t].x, kk.x, acc[t][c]);
                    acc[t][c] = fmaf(qq[t].y, kk.y, acc[t][c]);
                }
            }
        }

        // Scores: scale, accumulate softmax denom, branchless sorted top-5 insert.
#pragma unroll
        for (int t = 0; t < TQ; ++t) {
#pragma unroll
            for (int c = 0; c < CB; ++c) {
                float s = acc[t][c] * 0.125f;       // / TEMPERATURE
                Z[t] += __expf(s);                  // scores ~N(0,1): no overflow risk
                int col = g * TCOLS + c * 64 + lane;
                bool b0 = s > tv[t][0];
                bool b1 = s > tv[t][1];
                bool b2 = s > tv[t][2];
                bool b3 = s > tv[t][3];
                bool b4 = s > tv[t][4];
                tv[t][4] = b4 ? (b3 ? tv[t][3] : s)   : tv[t][4];
                tc[t][4] = b4 ? (b3 ? tc[t][3] : col) : tc[t][4];
                tv[t][3] = b3 ? (b2 ? tv[t][2] : s)   : tv[t][3];
                tc[t][3] = b3 ? (b2 ? tc[t][2] : col) : tc[t][3];
                tv[t][2] = b2 ? (b1 ? tv[t][1] : s)   : tv[t][2];
                tc[t][2] = b2 ? (b1 ? tc[t][1] : col) : tc[t][2];
                tv[t][1] = b1 ? (b0 ? tv[t][0] : s)   : tv[t][1];
                tc[t][1] = b1 ? (b0 ? tc[t][0] : col) : tc[t][1];
                tv[t][0] = b0 ? s   : tv[t][0];
                tc[t][0] = b0 ? col : tc[t][0];
            }
        }
    }

    // Epilogue per query: merge Z + top-5 across the 64 lanes, sparsify, emit.
#pragma unroll
    for (int t = 0; t < TQ; ++t) {
        float z = Z[t];
#pragma unroll
        for (int off = 32; off >= 1; off >>= 1) z += __shfl_xor(z, off, 64);

        float gv[5]; int gc[5];
#pragma unroll
        for (int r = 0; r < 5; ++r) {
            float cv = tv[t][0]; int cc = tc[t][0];
#pragma unroll
            for (int off = 32; off >= 1; off >>= 1) {
                float ov = __shfl_xor(cv, off, 64);
                int   oc = __shfl_xor(cc, off, 64);
                if (ov > cv || (ov == cv && oc < cc)) { cv = ov; cc = oc; }
            }
            gv[r] = cv; gc[r] = cc;
            // Pop from the (unique) owner lane; columns are lane-partitioned.
            if (tc[t][0] == cc) {
                tv[t][0] = tv[t][1]; tc[t][0] = tc[t][1];
                tv[t][1] = tv[t][2]; tc[t][1] = tc[t][2];
                tv[t][2] = tv[t][3]; tc[t][2] = tc[t][3];
                tv[t][3] = tv[t][4]; tc[t][3] = tc[t][4];
                tv[t][4] = -INFINITY; tc[t][4] = -1;
            }
        }

        float invz = 1.0f / z;
        float a0 = __expf(gv[0]) * invz;
        float a1 = __expf(gv[1]) * invz;
        float a2 = __expf(gv[2]) * invz;
        float a3 = __expf(gv[3]) * invz;
        float a4 = __expf(gv[4]) * invz;
        float delta = a4 + 1e-7f;                // k-th largest + EPS
        float w0 = fmaxf(a0 - delta, 0.f);
        float w1 = fmaxf(a1 - delta, 0.f);
        float w2 = fmaxf(a2 - delta, 0.f);
        float w3 = fmaxf(a3 - delta, 0.f);
        // All non-top-4 entries clamp to exactly 0, so row sum == w0+..+w3.
        float inv = 1.0f / (w0 + w1 + w2 + w3 + 1e-7f);
        w0 *= inv; w1 *= inv; w2 *= inv; w3 *= inv;

        const int qi = qblock + wid * TQ + t;
        // out row: lane == d index (D == 64). Gather <=4 V rows, coalesced.
        float o = w0 * vb[(size_t)gc[0] * D + lane]
                + w1 * vb[(size_t)gc[1] * D + lane]
                + w2 * vb[(size_t)gc[2] * D + lane]
                + w3 * vb[(size_t)gc[3] * D + lane];
        outg[(size_t)qi * D + lane] = o;

        // Scatter the <=4 nonzeros into the (pre-zeroed) dense attn row.
        if (lane < 4) {
            float wv = lane == 0 ? w0 : lane == 1 ? w1 : lane == 2 ? w2 : w3;
            int   cs = lane == 0 ? gc[0] : lane == 1 ? gc[1] : lane == 2 ? gc[2] : gc[3];
            attng[(size_t)qi * L + cs] = wv;
        }
    }
}

extern "C" void kernel_launch(void* const* d_in, const int* in_sizes, int n_in,
                              void* d_out, int out_size, void* d_ws, size_t ws_size,
                              hipStream_t stream) {
    const float* q = (const float*)d_in[0];
    const float* k = (const float*)d_in[1];
    const float* v = (const float*)d_in[2];
    float* out = (float*)d_out;

    const size_t out_elems  = (size_t)NB * L * D;         // 1,048,576
    const size_t attn_elems = (size_t)NB * L * L;         // 67,108,864

    // 1) zero the dense attn region (it is re-poisoned before every launch)
    float4* attn4 = (float4*)(out + out_elems);
    unsigned int n4 = (unsigned int)(attn_elems / 4);
    zero_kernel<<<2048, 256, 0, stream>>>(attn4, n4);

    // 2) fused score/softmax/top-k/PV kernel: 32 queries per 256-thread block
    dim3 grid(NB * L / 32);                               // 512 blocks
    sparse_attn_kernel<<<grid, 256, 0, stream>>>(q, k, v, out);
}

// Round 2
// 610.511 us; speedup vs baseline: 1.0811x; 1.0811x over previous
//
#include <hip/hip_runtime.h>
#include <math.h>

#define NB 4
#define L 4096
#define D 64
#define TQ 4          // queries per wave (16 per block)
#define QPB 16        // queries per block
#define CB 2          // columns per lane per tile
#define TCOLS 128     // K-tile columns (CB * 64)
#define NTILES (L / TCOLS)

__global__ __launch_bounds__(256, 4)
void sparse_attn_kernel(const float* __restrict__ qg,
                        const float* __restrict__ kg,
                        const float* __restrict__ vg,
                        float* __restrict__ outg) {
    // K tile: [col][dh] as float2. Row stride 33 float2 (66 floats):
    // lane address delta 66*4B -> bank stride 2 -> 2-way aliasing (free, m136).
    __shared__ float2 skt[TCOLS][D / 2 + 1];
    __shared__ float  sq[QPB][D];

    const int tid  = threadIdx.x;
    const int lane = tid & 63;
    const int wid  = tid >> 6;
    const int qblock = blockIdx.x * QPB;
    const int b = qblock >> 12;                  // qblock / L (uniform per block)
    const float* kb = kg + (size_t)b * L * D;
    const float* vb = vg + (size_t)b * L * D;
    float* attng = outg + (size_t)NB * L * D;    // attn region follows out region

    // Fused zero-fill of this block's 16 dense attn rows (d_out is poisoned
    // 0xAA before every launch). 16*4096 floats = 16384 float4 / 256 threads.
    {
        float4* zrow = (float4*)(attng + (size_t)qblock * L);
        float4 z = make_float4(0.f, 0.f, 0.f, 0.f);
#pragma unroll
        for (int j = 0; j < (QPB * L / 4) / 256; ++j)
            zrow[tid + j * 256] = z;
    }

    // Stage Q (16 rows x 64) -- coalesced
    for (int i = tid; i < QPB * D; i += 256)
        sq[i >> 6][i & 63] = qg[(size_t)qblock * D + i];

    float Z[TQ];
    float tv[TQ][5];
    int   tc[TQ][5];
#pragma unroll
    for (int t = 0; t < TQ; ++t) {
        Z[t] = 0.f;
#pragma unroll
        for (int i = 0; i < 5; ++i) { tv[t][i] = -INFINITY; tc[t][i] = -1; }
    }

    for (int g = 0; g < NTILES; ++g) {
        __syncthreads();
        // Stage K tile: cols [g*TCOLS, (g+1)*TCOLS). Coalesced float2 loads.
        for (int i = tid; i < TCOLS * (D / 2); i += 256) {
            int col = i >> 5;          // 32 float2 per column
            int dh  = i & 31;
            skt[col][dh] = *(const float2*)(kb + (size_t)(g * TCOLS + col) * D + dh * 2);
        }
        __syncthreads();

        float acc[TQ][CB];
#pragma unroll
        for (int t = 0; t < TQ; ++t)
#pragma unroll
            for (int c = 0; c < CB; ++c) acc[t][c] = 0.f;

#pragma unroll 4
        for (int dh = 0; dh < D / 2; ++dh) {
            float2 qq[TQ];
#pragma unroll
            for (int t = 0; t < TQ; ++t)
                qq[t] = *(const float2*)&sq[wid * TQ + t][dh * 2];  // LDS broadcast
#pragma unroll
            for (int c = 0; c < CB; ++c) {
                float2 kk = skt[c * 64 + lane][dh];
#pragma unroll
                for (int t = 0; t < TQ; ++t) {
                    acc[t][c] = fmaf(qq[t].x, kk.x, acc[t][c]);
                    acc[t][c] = fmaf(qq[t].y, kk.y, acc[t][c]);
                }
            }
        }

        // Scores: scale, accumulate softmax denom, branchless sorted top-5 insert.
#pragma unroll
        for (int t = 0; t < TQ; ++t) {
#pragma unroll
            for (int c = 0; c < CB; ++c) {
                float s = acc[t][c] * 0.125f;       // / TEMPERATURE
                Z[t] += __expf(s);                  // scores ~N(0,1): no overflow
                int col = g * TCOLS + c * 64 + lane;
                bool b0 = s > tv[t][0];
                bool b1 = s > tv[t][1];
                bool b2 = s > tv[t][2];
                bool b3 = s > tv[t][3];
                bool b4 = s > tv[t][4];
                tv[t][4] = b4 ? (b3 ? tv[t][3] : s)   : tv[t][4];
                tc[t][4] = b4 ? (b3 ? tc[t][3] : col) : tc[t][4];
                tv[t][3] = b3 ? (b2 ? tv[t][2] : s)   : tv[t][3];
                tc[t][3] = b3 ? (b2 ? tc[t][2] : col) : tc[t][3];
                tv[t][2] = b2 ? (b1 ? tv[t][1] : s)   : tv[t][2];
                tc[t][2] = b2 ? (b1 ? tc[t][1] : col) : tc[t][2];
                tv[t][1] = b1 ? (b0 ? tv[t][0] : s)   : tv[t][1];
                tc[t][1] = b1 ? (b0 ? tc[t][0] : col) : tc[t][1];
                tv[t][0] = b0 ? s   : tv[t][0];
                tc[t][0] = b0 ? col : tc[t][0];
            }
        }
    }

    // Epilogue per query: merge Z + top-5 across the 64 lanes, sparsify, emit.
#pragma unroll
    for (int t = 0; t < TQ; ++t) {
        float z = Z[t];
#pragma unroll
        for (int off = 32; off >= 1; off >>= 1) z += __shfl_xor(z, off, 64);

        float gv[5]; int gc[5];
#pragma unroll
        for (int r = 0; r < 5; ++r) {
            float cv = tv[t][0]; int cc = tc[t][0];
#pragma unroll
            for (int off = 32; off >= 1; off >>= 1) {
                float ov = __shfl_xor(cv, off, 64);
                int   oc = __shfl_xor(cc, off, 64);
                if (ov > cv || (ov == cv && oc < cc)) { cv = ov; cc = oc; }
            }
            gv[r] = cv; gc[r] = cc;
            // Pop from the (unique) owner lane; columns are lane-partitioned.
            if (tc[t][0] == cc) {
                tv[t][0] = tv[t][1]; tc[t][0] = tc[t][1];
                tv[t][1] = tv[t][2]; tc[t][1] = tc[t][2];
                tv[t][2] = tv[t][3]; tc[t][2] = tc[t][3];
                tv[t][3] = tv[t][4]; tc[t][3] = tc[t][4];
                tv[t][4] = -INFINITY; tc[t][4] = -1;
            }
        }

        float invz = 1.0f / z;
        float a0 = __expf(gv[0]) * invz;
        float a1 = __expf(gv[1]) * invz;
        float a2 = __expf(gv[2]) * invz;
        float a3 = __expf(gv[3]) * invz;
        float a4 = __expf(gv[4]) * invz;
        float delta = a4 + 1e-7f;                // k-th largest + EPS
        float w0 = fmaxf(a0 - delta, 0.f);
        float w1 = fmaxf(a1 - delta, 0.f);
        float w2 = fmaxf(a2 - delta, 0.f);
        float w3 = fmaxf(a3 - delta, 0.f);
        // All non-top-4 entries clamp to exactly 0, so row sum == w0+..+w3.
        float inv = 1.0f / (w0 + w1 + w2 + w3 + 1e-7f);
        w0 *= inv; w1 *= inv; w2 *= inv; w3 *= inv;

        const int qi = qblock + wid * TQ + t;
        // out row: lane == d index (D == 64). Gather <=4 V rows, coalesced.
        float o = w0 * vb[(size_t)gc[0] * D + lane]
                + w1 * vb[(size_t)gc[1] * D + lane]
                + w2 * vb[(size_t)gc[2] * D + lane]
                + w3 * vb[(size_t)gc[3] * D + lane];
        outg[(size_t)qi * D + lane] = o;

        // Scatter the <=4 nonzeros into the (block-zeroed) dense attn row.
        // Ordering vs the zero-fill: every __syncthreads() in the tile loop
        // drains vmcnt before s_barrier, so zero-stores precede these.
        if (lane < 4) {
            float wv = lane == 0 ? w0 : lane == 1 ? w1 : lane == 2 ? w2 : w3;
            int   cs = lane == 0 ? gc[0] : lane == 1 ? gc[1] : lane == 2 ? gc[2] : gc[3];
            attng[(size_t)qi * L + cs] = wv;
        }
    }
}

extern "C" void kernel_launch(void* const* d_in, const int* in_sizes, int n_in,
                              void* d_out, int out_size, void* d_ws, size_t ws_size,
                              hipStream_t stream) {
    const float* q = (const float*)d_in[0];
    const float* k = (const float*)d_in[1];
    const float* v = (const float*)d_in[2];
    float* out = (float*)d_out;

    dim3 grid(NB * L / QPB);                              // 1024 blocks = 4/CU
    sparse_attn_kernel<<<grid, 256, 0, stream>>>(q, k, v, out);
}

// Round 4
// 343.913 us; speedup vs baseline: 1.9191x; 1.7752x over previous
//
#include <hip/hip_runtime.h>
#include <math.h>

#define NB 4
#define L 4096
#define D 64
#define QPB 64            // query rows per block (4 waves x 16)
#define TCOLS 128         // K-tile columns
#define NT (L / TCOLS)    // 32 tiles
#define KCH (TCOLS + 1)   // K LDS chunk-row stride (16B chunks) -> bank shift 4
#define QCH (QPB + 1)     // Q LDS chunk-row stride

typedef __attribute__((ext_vector_type(8))) short short8;   // 8 bf16 = 4 VGPRs
typedef __attribute__((ext_vector_type(4))) float floatx4;

// fp32 -> (hi, lo) bf16 pair: hi = RNE(x), lo = RNE(x - hi). x - hi is exact
// (Sterbenz: hi within 0.2% of x), so hi+lo carries ~17 mantissa bits.
static __device__ inline ushort2 f2bf2(float x) {
    unsigned int u = __builtin_bit_cast(unsigned int, x);
    unsigned int uh = u + (0x7FFFu + ((u >> 16) & 1u));
    unsigned short h = (unsigned short)(uh >> 16);
    float hf = __builtin_bit_cast(float, (unsigned int)h << 16);
    float r = x - hf;
    unsigned int v = __builtin_bit_cast(unsigned int, r);
    unsigned short l = (unsigned short)((v + (0x7FFFu + ((v >> 16) & 1u))) >> 16);
    ushort2 p; p.x = h; p.y = l; return p;
}

__global__ __launch_bounds__(256, 1)
void sparse_attn_kernel(const float* __restrict__ qg,
                        const float* __restrict__ kg,
                        const float* __restrict__ vg,
                        float* __restrict__ outg) {
    // K tiles (double-buffered) + Q, bf16 hi/lo planes, 16B chunks [cq][col].
    // Reads: consecutive lanes -> consecutive 16B chunks (2-way, free).
    // Writes: chunk-row stride 129/65 -> bank shift 4 per cq (conflict-free).
    __shared__ unsigned short skth[2][8 * KCH * 8];
    __shared__ unsigned short sktl[2][8 * KCH * 8];
    __shared__ unsigned short sqh[8 * QCH * 8];
    __shared__ unsigned short sql[8 * QCH * 8];

    const int tid  = threadIdx.x;
    const int lane = tid & 63;
    const int wid  = tid >> 6;
    const int c16  = lane & 15;
    const int quad = lane >> 4;

    // XCD swizzle: blocks with blockIdx%8==x share one batch's K/V (2 MB < L2)
    const int sblk  = (blockIdx.x & 7) * 32 + (blockIdx.x >> 3);
    const int qbase = sblk * QPB;
    const int b     = qbase >> 12;                 // batch (uniform per block)
    const float* kb = kg + (size_t)b * L * D;
    const float* vb = vg + (size_t)b * L * D;
    float* attng = outg + (size_t)NB * L * D;      // dense attn region
    float4* zrow = (float4*)(attng + (size_t)qbase * L);   // 64 rows to zero

    // ---- Stage Q: 64 rows x 64 d, fp32 -> bf16 hi/lo LDS
#pragma unroll
    for (int i = 0; i < 4; ++i) {
        int f   = tid + i * 256;                   // [0, 1024)
        int row = f >> 4, f4 = f & 15;
        float4 qv = *(const float4*)(qg + (size_t)(qbase + row) * D + f4 * 4);
        ushort2 p0 = f2bf2(qv.x), p1 = f2bf2(qv.y), p2 = f2bf2(qv.z), p3 = f2bf2(qv.w);
        int base = (((f4 >> 1) * QCH) + row) * 8 + (f4 & 1) * 4;
        ushort4 ph; ph.x = p0.x; ph.y = p1.x; ph.z = p2.x; ph.w = p3.x;
        ushort4 pl; pl.x = p0.y; pl.y = p1.y; pl.z = p2.y; pl.w = p3.y;
        *(ushort4*)&sqh[base] = ph;
        *(ushort4*)&sql[base] = pl;
    }

    // ---- K tile 0: global -> regs -> bf16 hi/lo -> LDS buf0; prefetch tile 1
    float4 r8[8];
#pragma unroll
    for (int i = 0; i < 8; ++i)
        r8[i] = *(const float4*)(kb + (tid + i * 256) * 4);
#pragma unroll
    for (int i = 0; i < 8; ++i) {
        int f = tid + i * 256;                     // [0, 2048)
        int col = f >> 4, f4 = f & 15;
        ushort2 p0 = f2bf2(r8[i].x), p1 = f2bf2(r8[i].y), p2 = f2bf2(r8[i].z), p3 = f2bf2(r8[i].w);
        int base = (((f4 >> 1) * KCH) + col) * 8 + (f4 & 1) * 4;
        ushort4 ph; ph.x = p0.x; ph.y = p1.x; ph.z = p2.x; ph.w = p3.x;
        ushort4 pl; pl.x = p0.y; pl.y = p1.y; pl.z = p2.y; pl.w = p3.y;
        *(ushort4*)&skth[0][base] = ph;
        *(ushort4*)&sktl[0][base] = pl;
    }
#pragma unroll
    for (int i = 0; i < 8; ++i)
        r8[i] = *(const float4*)(kb + (size_t)1 * TCOLS * D + (tid + i * 256) * 4);

    __syncthreads();

    // ---- Q fragments (loop-invariant): A[m=lane&15][k=quad*8+j], 2 K-steps
    const short8 a0h = *(const short8*)&sqh[((quad)     * QCH + wid * 16 + c16) * 8];
    const short8 a1h = *(const short8*)&sqh[((4 + quad) * QCH + wid * 16 + c16) * 8];
    const short8 a0l = *(const short8*)&sql[((quad)     * QCH + wid * 16 + c16) * 8];
    const short8 a1l = *(const short8*)&sql[((4 + quad) * QCH + wid * 16 + c16) * 8];

    float Z[4] = {0.f, 0.f, 0.f, 0.f};
    float tv[4][5];
    int   tc[4][5];
#pragma unroll
    for (int r = 0; r < 4; ++r)
#pragma unroll
        for (int i = 0; i < 5; ++i) { tv[r][i] = -INFINITY; tc[r][i] = -1; }

    for (int g = 0; g < NT; ++g) {
        const unsigned short* kbh = skth[g & 1];
        const unsigned short* kbl = sktl[g & 1];

        // ---- compute: 8 col-groups of 16; scores for 16 rows x 128 cols
#pragma unroll
        for (int cg = 0; cg < 8; ++cg) {
            short8 b0h = *(const short8*)&kbh[((quad)     * KCH + cg * 16 + c16) * 8];
            short8 b1h = *(const short8*)&kbh[((4 + quad) * KCH + cg * 16 + c16) * 8];
            short8 b0l = *(const short8*)&kbl[((quad)     * KCH + cg * 16 + c16) * 8];
            short8 b1l = *(const short8*)&kbl[((4 + quad) * KCH + cg * 16 + c16) * 8];
            floatx4 acc = {0.f, 0.f, 0.f, 0.f};
            acc = __builtin_amdgcn_mfma_f32_16x16x32_bf16(a0h, b0h, acc, 0, 0, 0);
            acc = __builtin_amdgcn_mfma_f32_16x16x32_bf16(a1h, b1h, acc, 0, 0, 0);
            acc = __builtin_amdgcn_mfma_f32_16x16x32_bf16(a0l, b0h, acc, 0, 0, 0);
            acc = __builtin_amdgcn_mfma_f32_16x16x32_bf16(a1l, b1h, acc, 0, 0, 0);
            acc = __builtin_amdgcn_mfma_f32_16x16x32_bf16(a0h, b0l, acc, 0, 0, 0);
            acc = __builtin_amdgcn_mfma_f32_16x16x32_bf16(a1h, b1l, acc, 0, 0, 0);
            int col = g * TCOLS + cg * 16 + c16;
#pragma unroll
            for (int r = 0; r < 4; ++r) {
                float s = acc[r] * 0.125f;          // / TEMPERATURE
                Z[r] += __expf(s);
                bool q0 = s > tv[r][0];
                bool q1 = s > tv[r][1];
                bool q2 = s > tv[r][2];
                bool q3 = s > tv[r][3];
                bool q4 = s > tv[r][4];
                tv[r][4] = q4 ? (q3 ? tv[r][3] : s)   : tv[r][4];
                tc[r][4] = q4 ? (q3 ? tc[r][3] : col) : tc[r][4];
                tv[r][3] = q3 ? (q2 ? tv[r][2] : s)   : tv[r][3];
                tc[r][3] = q3 ? (q2 ? tc[r][2] : col) : tc[r][3];
                tv[r][2] = q2 ? (q1 ? tv[r][1] : s)   : tv[r][2];
                tc[r][2] = q2 ? (q1 ? tc[r][1] : col) : tc[r][2];
                tv[r][1] = q1 ? (q0 ? tv[r][0] : s)   : tv[r][1];
                tc[r][1] = q1 ? (q0 ? tc[r][0] : col) : tc[r][1];
                tv[r][0] = q0 ? s   : tv[r][0];
                tc[r][0] = q0 ? col : tc[r][0];
            }
        }

        // ---- zero-fill slice of this block's 64 dense attn rows (overlaps)
        float4 zv = make_float4(0.f, 0.f, 0.f, 0.f);
#pragma unroll
        for (int j = 0; j < 8; ++j)
            zrow[(size_t)(g * 8 + j) * 256 + tid] = zv;

        // ---- write tile g+1 (from regs), prefetch tile g+2
        if (g + 1 < NT) {
#pragma unroll
            for (int i = 0; i < 8; ++i) {
                int f = tid + i * 256;
                int col = f >> 4, f4 = f & 15;
                ushort2 p0 = f2bf2(r8[i].x), p1 = f2bf2(r8[i].y),
                        p2 = f2bf2(r8[i].z), p3 = f2bf2(r8[i].w);
                int base = (((f4 >> 1) * KCH) + col) * 8 + (f4 & 1) * 4;
                ushort4 ph; ph.x = p0.x; ph.y = p1.x; ph.z = p2.x; ph.w = p3.x;
                ushort4 pl; pl.x = p0.y; pl.y = p1.y; pl.z = p2.y; pl.w = p3.y;
                *(ushort4*)&skth[(g + 1) & 1][base] = ph;
                *(ushort4*)&sktl[(g + 1) & 1][base] = pl;
            }
            if (g + 2 < NT) {
#pragma unroll
                for (int i = 0; i < 8; ++i)
                    r8[i] = *(const float4*)(kb + (size_t)(g + 2) * TCOLS * D + (tid + i * 256) * 4);
            }
        }
        __syncthreads();   // buf[(g+1)&1] visible; also drains zero stores
    }

    // ---- epilogue: 4 rows per lane; merge across the 16 lanes of the quad
#pragma unroll
    for (int r = 0; r < 4; ++r) {
        float z = Z[r];
        z += __shfl_xor(z, 1, 64);
        z += __shfl_xor(z, 2, 64);
        z += __shfl_xor(z, 4, 64);
        z += __shfl_xor(z, 8, 64);

        float gv[5]; int gc[5];
#pragma unroll
        for (int k5 = 0; k5 < 5; ++k5) {
            float cv = tv[r][0]; int cc = tc[r][0];
#pragma unroll
            for (int m = 8; m >= 1; m >>= 1) {
                float ov = __shfl_xor(cv, m, 64);
                int   oc = __shfl_xor(cc, m, 64);
                if (ov > cv || (ov == cv && oc < cc)) { cv = ov; cc = oc; }
            }
            gv[k5] = cv; gc[k5] = cc;
            if (tc[r][0] == cc) {                   // unique owner pops
                tv[r][0] = tv[r][1]; tc[r][0] = tc[r][1];
                tv[r][1] = tv[r][2]; tc[r][1] = tc[r][2];
                tv[r][2] = tv[r][3]; tc[r][2] = tc[r][3];
                tv[r][3] = tv[r][4]; tc[r][3] = tc[r][4];
                tv[r][4] = -INFINITY; tc[r][4] = -1;
            }
        }

        float invz = 1.0f / z;
        float e0 = __expf(gv[0]) * invz;
        float e1 = __expf(gv[1]) * invz;
        float e2 = __expf(gv[2]) * invz;
        float e3 = __expf(gv[3]) * invz;
        float e4 = __expf(gv[4]) * invz;
        float delta = e4 + 1e-7f;
        float w0 = fmaxf(e0 - delta, 0.f);
        float w1 = fmaxf(e1 - delta, 0.f);
        float w2 = fmaxf(e2 - delta, 0.f);
        float w3 = fmaxf(e3 - delta, 0.f);
        float inv = 1.0f / (w0 + w1 + w2 + w3 + 1e-7f);
        w0 *= inv; w1 *= inv; w2 *= inv; w3 *= inv;

        const int rowabs = qbase + wid * 16 + quad * 4 + r;

        // out row: 16 lanes x float4 cover D=64
        const float4 v0 = *(const float4*)(vb + (size_t)gc[0] * D + c16 * 4);
        const float4 v1 = *(const float4*)(vb + (size_t)gc[1] * D + c16 * 4);
        const float4 v2 = *(const float4*)(vb + (size_t)gc[2] * D + c16 * 4);
        const float4 v3 = *(const float4*)(vb + (size_t)gc[3] * D + c16 * 4);
        float4 o;
        o.x = w0 * v0.x + w1 * v1.x + w2 * v2.x + w3 * v3.x;
        o.y = w0 * v0.y + w1 * v1.y + w2 * v2.y + w3 * v3.y;
        o.z = w0 * v0.z + w1 * v1.z + w2 * v2.z + w3 * v3.z;
        o.w = w0 * v0.w + w1 * v1.w + w2 * v2.w + w3 * v3.w;
        *(float4*)(outg + (size_t)rowabs * D + c16 * 4) = o;

        // scatter <=4 nonzeros into the (zeroed) dense attn row; zero stores
        // were drained by the final __syncthreads (vmcnt(0) before barrier).
        if (c16 < 4) {
            float wv = c16 == 0 ? w0 : c16 == 1 ? w1 : c16 == 2 ? w2 : w3;
            int   cs = c16 == 0 ? gc[0] : c16 == 1 ? gc[1] : c16 == 2 ? gc[2] : gc[3];
            attng[(size_t)rowabs * L + cs] = wv;
        }
    }
}

extern "C" void kernel_launch(void* const* d_in, const int* in_sizes, int n_in,
                              void* d_out, int out_size, void* d_ws, size_t ws_size,
                              hipStream_t stream) {
    const float* q = (const float*)d_in[0];
    const float* k = (const float*)d_in[1];
    const float* v = (const float*)d_in[2];
    float* out = (float*)d_out;

    dim3 grid(NB * L / QPB);                       // 256 blocks = 1 per CU
    sparse_attn_kernel<<<grid, 256, 0, stream>>>(q, k, v, out);
}